// Round 3
// baseline (2526.240 us; speedup 1.0000x reference)
//
#include <hip/hip_runtime.h>
#include <hip/hip_bf16.h>
#include <cfloat>

// B=32, N=2048 -> BN=65536 rows, D=128, K=1024 codes
#define DIM 128
#define NCODES 1024
#define MTILE 128          // rows per block (4 waves x 32 rows)
#define ROWS_PER_WAVE 32
#define NSUB 2             // 16-row M-subtiles per wave
#define KSTEPS 4           // K=128 / 32
#define GROUPS (NCODES / 16)
#define LOSS_SCALE (12.5f / 8388608.0f)

typedef _Float16 f16x8 __attribute__((ext_vector_type(8)));
typedef float f32x4 __attribute__((ext_vector_type(4)));

// prep: E (fp32) -> Ehi,Elo (f16 split) + enorm = ||E_k||^2; block 0 zeroes loss
__global__ __launch_bounds__(128) void prep_kernel(const float* __restrict__ E,
                                                   _Float16* __restrict__ Ehi,
                                                   _Float16* __restrict__ Elo,
                                                   float* __restrict__ enorm,
                                                   float* __restrict__ loss) {
    const int k = blockIdx.x;
    const int d = threadIdx.x;
    if (k == 0 && d == 0) *loss = 0.f;
    float e = E[k * DIM + d];
    _Float16 h = (_Float16)e;
    Ehi[k * DIM + d] = h;
    Elo[k * DIM + d] = (_Float16)(e - (float)h);
    float sq = e * e;
#pragma unroll
    for (int off = 32; off > 0; off >>= 1) sq += __shfl_down(sq, off, 64);
    __shared__ float s2[2];
    if ((d & 63) == 0) s2[d >> 6] = sq;
    __syncthreads();
    if (d == 0) enorm[k] = s2[0] + s2[1];
}

// Fused MFMA dist + argmin + gather + loss.
// dist'(m,k) = ||E_k||^2 - 2 z_m.E_k via C=enorm, A=-2z (f16 hi/lo), B=E^T (f16 hi/lo).
// 3 cross products (hh, hl, lh; lo*lo ~2^-22 rel, dropped) in SEPARATE accumulator
// chains (6 independent MFMA chains/wave, depth 4) + double-buffered B prefetch.
__global__ __launch_bounds__(256, 2) void vq_kernel(const float* __restrict__ z,
                                                    const _Float16* __restrict__ Ehi,
                                                    const _Float16* __restrict__ Elo,
                                                    const float* __restrict__ enorm,
                                                    const float* __restrict__ E,
                                                    float* __restrict__ out,
                                                    float* __restrict__ loss) {
    const int t = threadIdx.x;
    const int lane = t & 63;
    const int wave = t >> 6;
    const int m16 = lane & 15;   // A row within subtile / B,C code col
    const int quad = lane >> 4;  // k-group for A/B; row-group for C

    __shared__ float s_enorm[NCODES];
    __shared__ float s_znorm[MTILE];
    __shared__ float s_bv[MTILE][17];
    __shared__ int s_bi[MTILE][17];
    __shared__ int s_ind[MTILE];
    __shared__ float s_wsum[4];

    for (int i = t; i < NCODES; i += 256) s_enorm[i] = enorm[i];

    // ---- A fragments: wave's 32 rows, K=128, scaled by -2, f16 hi/lo split.
    // A layout (16x16x32): lane holds A[m=lane&15][k=quad*8+j], j=0..7.
    f16x8 Ahi[NSUB][KSTEPS], Alo[NSUB][KSTEPS];
    float znp[NSUB] = {0.f, 0.f};
    const int rowbase = blockIdx.x * MTILE + wave * ROWS_PER_WAVE;
#pragma unroll
    for (int s = 0; s < NSUB; ++s) {
        const int row = rowbase + s * 16 + m16;
        const float* zp = z + (size_t)row * DIM + quad * 8;
#pragma unroll
        for (int ks = 0; ks < KSTEPS; ++ks) {
            float4 v0 = *(const float4*)(zp + ks * 32);
            float4 v1 = *(const float4*)(zp + ks * 32 + 4);
            float zv[8] = {v0.x, v0.y, v0.z, v0.w, v1.x, v1.y, v1.z, v1.w};
#pragma unroll
            for (int j = 0; j < 8; ++j) {
                znp[s] = fmaf(zv[j], zv[j], znp[s]);
                float tt = -2.f * zv[j];
                _Float16 h = (_Float16)tt;
                Ahi[s][ks][j] = h;
                Alo[s][ks][j] = (_Float16)(tt - (float)h);
            }
        }
    }
    // znorm: sum the 4 k-quads (lanes m16, m16+16, m16+32, m16+48)
#pragma unroll
    for (int s = 0; s < NSUB; ++s) {
        float v = znp[s];
        v += __shfl_xor(v, 16, 64);
        v += __shfl_xor(v, 32, 64);
        if (quad == 0) s_znorm[wave * ROWS_PER_WAVE + s * 16 + m16] = v;
    }
    __syncthreads();

    // ---- main loop over 64 groups of 16 codes
    float bestv[NSUB][4];
    int besti[NSUB][4];
#pragma unroll
    for (int s = 0; s < NSUB; ++s)
#pragma unroll
        for (int r = 0; r < 4; ++r) {
            bestv[s][r] = FLT_MAX;
            besti[s][r] = 0;
        }

    // B layout (16x16x32): lane holds B[k=quad*8+j][n=lane&15]
    const _Float16* bhp = Ehi + (size_t)m16 * DIM + quad * 8;
    const _Float16* blp = Elo + (size_t)m16 * DIM + quad * 8;

    f16x8 Bhi[2][KSTEPS], Blo[2][KSTEPS];
#pragma unroll
    for (int ks = 0; ks < KSTEPS; ++ks) {
        Bhi[0][ks] = *(const f16x8*)(bhp + ks * 32);
        Blo[0][ks] = *(const f16x8*)(blp + ks * 32);
    }

    for (int g = 0; g < GROUPS; ++g) {
        const int cur = g & 1;
        const int nxt = cur ^ 1;
        if (g + 1 < GROUPS) {  // prefetch next group's B into the other buffer
            const size_t boff = (size_t)(g + 1) * 16 * DIM;
#pragma unroll
            for (int ks = 0; ks < KSTEPS; ++ks) {
                Bhi[nxt][ks] = *(const f16x8*)(bhp + boff + ks * 32);
                Blo[nxt][ks] = *(const f16x8*)(blp + boff + ks * 32);
            }
        }
        const int n = g * 16 + m16;
        const float e = s_enorm[n];
        f32x4 acc_hh[NSUB], acc_hl[NSUB], acc_lh[NSUB];
#pragma unroll
        for (int s = 0; s < NSUB; ++s) {
            acc_hh[s] = (f32x4){e, e, e, e};
            acc_hl[s] = (f32x4){0.f, 0.f, 0.f, 0.f};
            acc_lh[s] = (f32x4){0.f, 0.f, 0.f, 0.f};
        }
#pragma unroll
        for (int ks = 0; ks < KSTEPS; ++ks) {
#pragma unroll
            for (int s = 0; s < NSUB; ++s) {
                acc_hl[s] = __builtin_amdgcn_mfma_f32_16x16x32_f16(Ahi[s][ks], Blo[cur][ks], acc_hl[s], 0, 0, 0);
                acc_lh[s] = __builtin_amdgcn_mfma_f32_16x16x32_f16(Alo[s][ks], Bhi[cur][ks], acc_lh[s], 0, 0, 0);
                acc_hh[s] = __builtin_amdgcn_mfma_f32_16x16x32_f16(Ahi[s][ks], Bhi[cur][ks], acc_hh[s], 0, 0, 0);
            }
        }
        // C layout: col = lane&15 (code n), row = quad*4 + reg
#pragma unroll
        for (int s = 0; s < NSUB; ++s)
#pragma unroll
            for (int r = 0; r < 4; ++r) {
                float d = acc_hh[s][r] + (acc_hl[s][r] + acc_lh[s][r]);
                if (d < bestv[s][r]) {  // strict <, ascending g => first-index tie rule
                    bestv[s][r] = d;
                    besti[s][r] = n;
                }
            }
    }

    // ---- cross-lane argmin: each row's 16 candidate lanes -> LDS
#pragma unroll
    for (int s = 0; s < NSUB; ++s)
#pragma unroll
        for (int r = 0; r < 4; ++r) {
            const int row = wave * ROWS_PER_WAVE + s * 16 + quad * 4 + r;
            s_bv[row][m16] = bestv[s][r];
            s_bi[row][m16] = besti[s][r];
        }
    __syncthreads();

    float lp = 0.f;
    if (t < MTILE) {
        float bv = s_bv[t][0];
        int bi = s_bi[t][0];
#pragma unroll
        for (int j = 1; j < 16; ++j) {
            float v = s_bv[t][j];
            int i = s_bi[t][j];
            if (v < bv || (v == bv && i < bi)) {  // lexicographic: min val, min index
                bv = v;
                bi = i;
            }
        }
        s_ind[t] = bi;
        lp = s_znorm[t] + bv;  // ||z-E||^2 = ||z||^2 + (||E||^2 - 2 z.E)
    }
#pragma unroll
    for (int off = 32; off > 0; off >>= 1) lp += __shfl_down(lp, off, 64);
    if (lane == 0) s_wsum[wave] = lp;
    __syncthreads();
    if (t == 0)
        atomicAdd(loss, (s_wsum[0] + s_wsum[1] + s_wsum[2] + s_wsum[3]) * LOSS_SCALE);

    // ---- gather-write z_q (STE forward == z_q), float4 coalesced, E is L2-hot
    const float4* E4 = (const float4*)E;
    float4* out4 = (float4*)(out + (size_t)blockIdx.x * (MTILE * DIM));
#pragma unroll
    for (int i = 0; i < (MTILE * DIM) / (256 * 4); ++i) {
        const int f = t + i * 256;  // float4 index within tile
        const int r = f >> 5;       // 32 float4 per row
        const int d = f & 31;
        out4[f] = E4[(size_t)s_ind[r] * 32 + d];
    }
}

extern "C" void kernel_launch(void* const* d_in, const int* in_sizes, int n_in,
                              void* d_out, int out_size, void* d_ws, size_t ws_size,
                              hipStream_t stream) {
    const float* z = (const float*)d_in[0];  // [BN,128] fp32
    const float* E = (const float*)d_in[1];  // [1024,128] fp32
    float* out = (float*)d_out;              // [BN*128] z_q + [1] loss
    float* loss = out + (size_t)(out_size - 1);
    _Float16* Ehi = (_Float16*)d_ws;                 // 256 KB
    _Float16* Elo = Ehi + (size_t)NCODES * DIM;      // 256 KB
    float* enorm = (float*)(Elo + (size_t)NCODES * DIM);  // 4 KB
    const int BN = in_sizes[0] / DIM;

    prep_kernel<<<NCODES, 128, 0, stream>>>(E, Ehi, Elo, enorm, loss);
    vq_kernel<<<BN / MTILE, 256, 0, stream>>>(z, Ehi, Elo, enorm, E, out, loss);
}

// Round 4
// 203.655 us; speedup vs baseline: 12.4045x; 12.4045x over previous
//
#include <hip/hip_runtime.h>
#include <hip/hip_bf16.h>
#include <cfloat>

// B=32, N=2048 -> BN=65536 rows, D=128, K=1024 codes
#define DIM 128
#define NCODES 1024
#define MTILE 128          // rows per block (4 waves x 32 rows)
#define ROWS_PER_WAVE 32
#define NSUB 2             // 16-row M-subtiles per wave
#define KSTEPS 4           // K=128 / 32
#define GROUPS (NCODES / 16)
#define LOSS_SCALE (12.5f / 8388608.0f)

typedef _Float16 f16x8 __attribute__((ext_vector_type(8)));
typedef float f32x4 __attribute__((ext_vector_type(4)));

// prep: E (fp32) -> Ehi,Elo (f16 split) + enorm = ||E_k||^2; block 0 zeroes loss
__global__ __launch_bounds__(128) void prep_kernel(const float* __restrict__ E,
                                                   _Float16* __restrict__ Ehi,
                                                   _Float16* __restrict__ Elo,
                                                   float* __restrict__ enorm,
                                                   float* __restrict__ loss) {
    const int k = blockIdx.x;
    const int d = threadIdx.x;
    if (k == 0 && d == 0) *loss = 0.f;
    float e = E[k * DIM + d];
    _Float16 h = (_Float16)e;
    Ehi[k * DIM + d] = h;
    Elo[k * DIM + d] = (_Float16)(e - (float)h);
    float sq = e * e;
#pragma unroll
    for (int off = 32; off > 0; off >>= 1) sq += __shfl_down(sq, off, 64);
    __shared__ float s2[2];
    if ((d & 63) == 0) s2[d >> 6] = sq;
    __syncthreads();
    if (d == 0) enorm[k] = s2[0] + s2[1];
}

// Fused MFMA dist + argmin + gather + loss.
// dist'(m,k) = ||E_k||^2 - 2 z_m.E_k via C=enorm, A=-2z (f16 hi/lo), B=E^T (f16 hi/lo).
// 3 cross products: acc_hh (init ||E||^2) and acc_c (hl+lh, init 0) -> 4 independent
// MFMA chains/wave. B double-buffer as STATICALLY-NAMED register arrays (the round-3
// Bhi[cur] runtime index forced the buffer to scratch -> 19x regression).
__global__ __launch_bounds__(256, 2) void vq_kernel(const float* __restrict__ z,
                                                    const _Float16* __restrict__ Ehi,
                                                    const _Float16* __restrict__ Elo,
                                                    const float* __restrict__ enorm,
                                                    const float* __restrict__ E,
                                                    float* __restrict__ out,
                                                    float* __restrict__ loss) {
    const int t = threadIdx.x;
    const int lane = t & 63;
    const int wave = t >> 6;
    const int m16 = lane & 15;   // A row within subtile / B,C code col
    const int quad = lane >> 4;  // k-group for A/B; row-group for C

    __shared__ float s_enorm[NCODES];
    __shared__ float s_znorm[MTILE];
    __shared__ float s_bv[MTILE][17];
    __shared__ int s_bi[MTILE][17];
    __shared__ int s_ind[MTILE];
    __shared__ float s_wsum[4];

    for (int i = t; i < NCODES; i += 256) s_enorm[i] = enorm[i];

    // ---- A fragments: wave's 32 rows, K=128, scaled by -2, f16 hi/lo split.
    // A layout (16x16x32): lane holds A[m=lane&15][k=quad*8+j], j=0..7.
    f16x8 Ahi[NSUB][KSTEPS], Alo[NSUB][KSTEPS];
    float znp[NSUB] = {0.f, 0.f};
    const int rowbase = blockIdx.x * MTILE + wave * ROWS_PER_WAVE;
#pragma unroll
    for (int s = 0; s < NSUB; ++s) {
        const int row = rowbase + s * 16 + m16;
        const float* zp = z + (size_t)row * DIM + quad * 8;
#pragma unroll
        for (int ks = 0; ks < KSTEPS; ++ks) {
            float4 v0 = *(const float4*)(zp + ks * 32);
            float4 v1 = *(const float4*)(zp + ks * 32 + 4);
            float zv[8] = {v0.x, v0.y, v0.z, v0.w, v1.x, v1.y, v1.z, v1.w};
#pragma unroll
            for (int j = 0; j < 8; ++j) {
                znp[s] = fmaf(zv[j], zv[j], znp[s]);
                float tt = -2.f * zv[j];
                _Float16 h = (_Float16)tt;
                Ahi[s][ks][j] = h;
                Alo[s][ks][j] = (_Float16)(tt - (float)h);
            }
        }
    }
    // znorm: sum the 4 k-quads (lanes m16, m16+16, m16+32, m16+48)
#pragma unroll
    for (int s = 0; s < NSUB; ++s) {
        float v = znp[s];
        v += __shfl_xor(v, 16, 64);
        v += __shfl_xor(v, 32, 64);
        if (quad == 0) s_znorm[wave * ROWS_PER_WAVE + s * 16 + m16] = v;
    }
    __syncthreads();

    // ---- main loop over 64 groups of 16 codes, 2x unrolled, ping-pong B regs
    float bestv[NSUB][4];
    int besti[NSUB][4];
#pragma unroll
    for (int s = 0; s < NSUB; ++s)
#pragma unroll
        for (int r = 0; r < 4; ++r) {
            bestv[s][r] = FLT_MAX;
            besti[s][r] = 0;
        }

    // B layout (16x16x32): lane holds B[k=quad*8+j][n=lane&15]
    const _Float16* bhp = Ehi + (size_t)m16 * DIM + quad * 8;
    const _Float16* blp = Elo + (size_t)m16 * DIM + quad * 8;

    f16x8 B0h[KSTEPS], B0l[KSTEPS], B1h[KSTEPS], B1l[KSTEPS];
#pragma unroll
    for (int ks = 0; ks < KSTEPS; ++ks) {
        B0h[ks] = *(const f16x8*)(bhp + ks * 32);
        B0l[ks] = *(const f16x8*)(blp + ks * 32);
    }

#define COMPUTE_GROUP(GIDX, BH, BL)                                                         \
    {                                                                                       \
        const int n = (GIDX)*16 + m16;                                                      \
        const float e = s_enorm[n];                                                         \
        f32x4 acc_hh[NSUB], acc_c[NSUB];                                                    \
        _Pragma("unroll") for (int s = 0; s < NSUB; ++s) {                                  \
            acc_hh[s] = (f32x4){e, e, e, e};                                                \
            acc_c[s] = (f32x4){0.f, 0.f, 0.f, 0.f};                                         \
        }                                                                                   \
        _Pragma("unroll") for (int ks = 0; ks < KSTEPS; ++ks) {                             \
            _Pragma("unroll") for (int s = 0; s < NSUB; ++s) {                              \
                acc_c[s] = __builtin_amdgcn_mfma_f32_16x16x32_f16(Ahi[s][ks], BL[ks],       \
                                                                  acc_c[s], 0, 0, 0);       \
                acc_c[s] = __builtin_amdgcn_mfma_f32_16x16x32_f16(Alo[s][ks], BH[ks],       \
                                                                  acc_c[s], 0, 0, 0);       \
                acc_hh[s] = __builtin_amdgcn_mfma_f32_16x16x32_f16(Ahi[s][ks], BH[ks],      \
                                                                   acc_hh[s], 0, 0, 0);     \
            }                                                                               \
        }                                                                                   \
        _Pragma("unroll") for (int s = 0; s < NSUB; ++s) _Pragma("unroll")                  \
            for (int r = 0; r < 4; ++r) {                                                   \
                float d = acc_hh[s][r] + acc_c[s][r];                                       \
                if (d < bestv[s][r]) { /* strict <, ascending g => first-index tie rule */  \
                    bestv[s][r] = d;                                                        \
                    besti[s][r] = n;                                                        \
                }                                                                           \
            }                                                                               \
    }

#define PREFETCH(GIDX, BH, BL)                                      \
    {                                                               \
        const size_t boff = (size_t)(GIDX)*16 * DIM;                \
        _Pragma("unroll") for (int ks = 0; ks < KSTEPS; ++ks) {     \
            BH[ks] = *(const f16x8*)(bhp + boff + ks * 32);         \
            BL[ks] = *(const f16x8*)(blp + boff + ks * 32);         \
        }                                                           \
    }

    for (int g = 0; g < GROUPS; g += 2) {
        PREFETCH(g + 1, B1h, B1l)
        COMPUTE_GROUP(g, B0h, B0l)
        if (g + 2 < GROUPS) PREFETCH(g + 2, B0h, B0l)
        COMPUTE_GROUP(g + 1, B1h, B1l)
    }
#undef COMPUTE_GROUP
#undef PREFETCH

    // ---- cross-lane argmin: each row's 16 candidate lanes -> LDS
#pragma unroll
    for (int s = 0; s < NSUB; ++s)
#pragma unroll
        for (int r = 0; r < 4; ++r) {
            const int row = wave * ROWS_PER_WAVE + s * 16 + quad * 4 + r;
            s_bv[row][m16] = bestv[s][r];
            s_bi[row][m16] = besti[s][r];
        }
    __syncthreads();

    float lp = 0.f;
    if (t < MTILE) {
        float bv = s_bv[t][0];
        int bi = s_bi[t][0];
#pragma unroll
        for (int j = 1; j < 16; ++j) {
            float v = s_bv[t][j];
            int i = s_bi[t][j];
            if (v < bv || (v == bv && i < bi)) {  // lexicographic: min val, min index
                bv = v;
                bi = i;
            }
        }
        s_ind[t] = bi;
        lp = s_znorm[t] + bv;  // ||z-E||^2 = ||z||^2 + (||E||^2 - 2 z.E)
    }
#pragma unroll
    for (int off = 32; off > 0; off >>= 1) lp += __shfl_down(lp, off, 64);
    if (lane == 0) s_wsum[wave] = lp;
    __syncthreads();
    if (t == 0)
        atomicAdd(loss, (s_wsum[0] + s_wsum[1] + s_wsum[2] + s_wsum[3]) * LOSS_SCALE);

    // ---- gather-write z_q (STE forward == z_q), float4 coalesced, E is L2-hot
    const float4* E4 = (const float4*)E;
    float4* out4 = (float4*)(out + (size_t)blockIdx.x * (MTILE * DIM));
#pragma unroll
    for (int i = 0; i < (MTILE * DIM) / (256 * 4); ++i) {
        const int f = t + i * 256;  // float4 index within tile
        const int r = f >> 5;       // 32 float4 per row
        const int d = f & 31;
        out4[f] = E4[(size_t)s_ind[r] * 32 + d];
    }
}

extern "C" void kernel_launch(void* const* d_in, const int* in_sizes, int n_in,
                              void* d_out, int out_size, void* d_ws, size_t ws_size,
                              hipStream_t stream) {
    const float* z = (const float*)d_in[0];  // [BN,128] fp32
    const float* E = (const float*)d_in[1];  // [1024,128] fp32
    float* out = (float*)d_out;              // [BN*128] z_q + [1] loss
    float* loss = out + (size_t)(out_size - 1);
    _Float16* Ehi = (_Float16*)d_ws;                 // 256 KB
    _Float16* Elo = Ehi + (size_t)NCODES * DIM;      // 256 KB
    float* enorm = (float*)(Elo + (size_t)NCODES * DIM);  // 4 KB
    const int BN = in_sizes[0] / DIM;

    prep_kernel<<<NCODES, 128, 0, stream>>>(E, Ehi, Elo, enorm, loss);
    vq_kernel<<<BN / MTILE, 256, 0, stream>>>(z, Ehi, Elo, enorm, E, out, loss);
}